// Round 4
// baseline (399.585 us; speedup 1.0000x reference)
//
#include <hip/hip_runtime.h>
#include <hip/hip_bf16.h>
#include <math.h>

// Problem constants (match reference)
#define BB  32
#define SS  4096
#define VV  256
#define DD  256
#define CC  2
#define WIN 64
#define NW  64   // SS/WIN

typedef unsigned short ushort_t;
typedef unsigned int   uint_t;
typedef __attribute__((ext_vector_type(8))) short short8;    // 8 bf16 (4 VGPRs)
typedef __attribute__((ext_vector_type(4))) float f32x4;

// Workspace layout (byte offsets). Base total 573440 B; +4 B done-counter if
// ws_size permits (guarded at launch, fallback = separate final kernel).
#define WS_ATHI_B 0u          // ushort Athi[64][64]   8192  (A-op layout: [t][s])
#define WS_ATLO_B 8192u       // ushort Atlo[64][64]   8192
#define WS_GPK_B  16384u      // uint   gpk[256][256]  262144 (hi<<16 | lo per elem)
#define WS_W2HI_B 278528u     // ushort W2hi[256][256] 131072
#define WS_W2LO_B 409600u     // ushort W2lo[256][256] 131072
#define WS_POOL_B 540672u     // float  pool[32][256]  32768
#define WS_CNT_B  573440u     // uint   done counter   4

#define HP 264    // H plane row stride in shorts (256 + 8 pad)

__device__ __forceinline__ float fast_tanh(float v) {
  float e = __expf(2.0f * v);
  return 1.0f - __fdividef(2.0f, e + 1.0f);
}

// Truncation-based bf16 split: v ~= hi + lo with |err| <= 2^-17 * |v|.
__device__ __forceinline__ uint_t split_pack(float v) {
  uint_t b  = __float_as_uint(v);
  uint_t hi = b & 0xffff0000u;
  float  r  = v - __uint_as_float(hi);
  uint_t lo = __float_as_uint(r) >> 16;
  return hi | lo;
}

// Pack hi/lo halves of two packed u32 into bf16 pair dwords via v_perm.
__device__ __forceinline__ uint_t perm_hi(uint_t p0, uint_t p1) {
  return __builtin_amdgcn_perm(p1, p0, 0x07060302u);
}
__device__ __forceinline__ uint_t perm_lo(uint_t p0, uint_t p1) {
  return __builtin_amdgcn_perm(p1, p0, 0x05040100u);
}

union u4s8 { uint_t u[4]; short8 v; };

// ---------------------------------------------------------------------------
// Prep grid (1090 blocks): as verified; blk 1 additionally zeroes the
// done-counter when enabled.
// ---------------------------------------------------------------------------
__global__ __launch_bounds__(256) void prep_kernel(
    const float* __restrict__ emb, const float* __restrict__ W1,
    const float* __restrict__ W2, char* __restrict__ ws, int have_cnt)
{
  const int blk = blockIdx.x;
  const int tid = threadIdx.x;
  ushort_t* Athi = (ushort_t*)(ws + WS_ATHI_B);
  ushort_t* Atlo = (ushort_t*)(ws + WS_ATLO_B);
  uint_t*   gpk  = (uint_t*)  (ws + WS_GPK_B);
  ushort_t* W2hi = (ushort_t*)(ws + WS_W2HI_B);
  ushort_t* W2lo = (ushort_t*)(ws + WS_W2LO_B);
  float*    pool = (float*)   (ws + WS_POOL_B);

  if (blk == 0) {
    if (tid < WIN) {
      const int s = tid;
      const float omega = 60.0f * 2.0f * 3.14159265358979323846f / 4095.0f;
      float row[WIN];
      float sum = 0.0f;
      for (int t = 0; t < WIN; ++t) {
        float e = expf(cosf(omega * (float)(s - t)));
        row[t] = e;
        sum += e;
      }
      const float inv = 1.0f / sum;
      for (int t = 0; t < WIN; ++t) {
        uint_t pk = split_pack(row[t] * inv);
        Athi[t * WIN + s] = (ushort_t)(pk >> 16);
        Atlo[t * WIN + s] = (ushort_t)(pk & 0xffffu);
      }
    }
  } else if (blk == 1) {
    for (int i = tid; i < BB * DD; i += 256) pool[i] = 0.0f;
    if (have_cnt && tid == 0) *(uint_t*)(ws + WS_CNT_B) = 0u;
  } else if (blk < 1026) {
    const int gv = blk - 2;            // 0..1023
    const int d0 = (gv & 15) * 16;     // 16 d-columns
    const int v0 = (gv >> 4) * 4;      // 4 v-rows
    __shared__ float er[4 * DD];       // 4 KB
    __shared__ float ps[4][16][17];    // padded partials
    *(float4*)(er + tid * 4) = *(const float4*)(emb + v0 * DD + tid * 4);
    __syncthreads();
    const int kq = tid & 15;           // k-strip: [16kq, 16kq+16)
    const int dl = tid >> 4;           // 0..15
    const int d  = d0 + dl;
    float4 wv[4];
    #pragma unroll
    for (int j = 0; j < 4; ++j)
      wv[j] = *(const float4*)(W1 + d * DD + 16 * kq + 4 * j);  // coalesced
    #pragma unroll
    for (int v = 0; v < 4; ++v) {
      float a = 0.0f;
      #pragma unroll
      for (int j = 0; j < 4; ++j) {
        float4 e = *(const float4*)(er + v * DD + 16 * kq + 4 * j);
        a += e.x * wv[j].x + e.y * wv[j].y + e.z * wv[j].z + e.w * wv[j].w;
      }
      ps[v][dl][kq] = a;
    }
    __syncthreads();
    if (tid < 64) {
      const int v = tid >> 4, dr = tid & 15;
      float s = 0.0f;
      #pragma unroll
      for (int k = 0; k < 16; ++k) s += ps[v][dr][k];
      gpk[(v0 + v) * DD + d0 + dr] = split_pack(s);
    }
  } else {
    const int c0 = (blk - 1026) * 4;
    #pragma unroll
    for (int i = 0; i < 4; ++i) {
      const int c = c0 + i;
      uint_t pk = split_pack(W2[c * DD + tid]);
      W2hi[c * DD + tid] = (ushort_t)(pk >> 16);
      W2lo[c * DD + tid] = (ushort_t)(pk & 0xffffu);
    }
  }
}

// Shared device body for the final math (identical op order to final_kernel).
__device__ __forceinline__ void final_math(
    const float* pool, const float* Wc, const float* bc, float* out,
    int b, int t, bool coherent)
{
  float p0 = 0.0f, p1 = 0.0f;
  #pragma unroll
  for (int j = 0; j < 4; ++j) {
    float pv;
    if (coherent)
      pv = __hip_atomic_load(&pool[b * DD + t + 64 * j],
                             __ATOMIC_RELAXED, __HIP_MEMORY_SCOPE_AGENT);
    else
      pv = pool[b * DD + t + 64 * j];
    p0 += pv * Wc[t + 64 * j];
    p1 += pv * Wc[DD + t + 64 * j];
  }
  #pragma unroll
  for (int off = 32; off; off >>= 1) {
    p0 += __shfl_xor(p0, off, 64);
    p1 += __shfl_xor(p1, off, 64);
  }
  if (t == 0) {
    out[b * CC + 0] = p0 * (1.0f / SS) + bc[0];
    out[b * CC + 1] = p1 * (1.0f / SS) + bc[1];
  }
}

// ---------------------------------------------------------------------------
// Main fused kernel — round-3 shape (one block per (b,n), 512 thr, 2 blk/CU,
// no spill) plus:
//  (a) 3-deep W2 prefetch ring in P4: preload k0=0,1; at step k0 prefetch
//      k0+2. Pipeline cover ~430 cyc > L2 latency (~200-400), removing the
//      per-k0 vmcnt stall that depth-1 prefetch (~220 cyc) left exposed.
//      +16 VGPR; total ~88 incl. AGPRs, within the 128 budget at 2 blk/CU.
//  (b) optional fused finale: last block (device-scope done counter, release/
//      acquire fences, coherent pool loads) computes out[] -> saves the
//      final_kernel launch. Enabled only if ws_size >= WS_CNT_B+4.
// SQ_LDS_BANK_CONFLICT (= 2^22 in every round, layout-invariant) is now
// treated as an op-mix artifact, not a lever.
// ---------------------------------------------------------------------------
__global__ __launch_bounds__(512, 4) void main_kernel(
    const int*      __restrict__ x,    const uint_t* __restrict__ gpk,
    const ushort_t* __restrict__ Athi, const ushort_t* __restrict__ Atlo,
    const float*    __restrict__ b1,
    const ushort_t* __restrict__ W2hi, const ushort_t* __restrict__ W2lo,
    const float*    __restrict__ b2,   float* __restrict__ pool,
    uint_t* __restrict__ done_cnt,     // may be null (no fused finale)
    const float* __restrict__ Wc, const float* __restrict__ bc,
    float* __restrict__ out)
{
  __shared__ ushort_t Hhi[WIN][HP];   // 33792 B
  __shared__ ushort_t Hlo[WIN][HP];   // 33792 B (total 67584 -> 2 blocks/CU)
  __shared__ int sh_last;

  const int tid  = threadIdx.x;
  const int lane = tid & 63;
  const int w    = tid >> 6;       // 0..7
  const int quad = lane >> 4;
  const int l16  = lane & 15;
  const int b = blockIdx.x >> 6;
  const int n = blockIdx.x & 63;

  const int dbase = 32 * w;        // this wave's d-slice (P2) == c-slice (P4)
  const int cbase = dbase;
  const int rsw   = (l16 & 8) << 1;   // P4 read un-swizzle (16 shorts)

  // --- P1: gather (packed u32), issued first so latency overlaps setup ---
  const int xv = x[b * SS + n * WIN + lane];
  uint_t q[2][2][8];
  #pragma unroll
  for (int k0 = 0; k0 < 2; ++k0) {
    const int sl = k0 * 32 + quad * 8;
    int xs[8];
    #pragma unroll
    for (int j = 0; j < 8; ++j) xs[j] = __shfl(xv, sl + j, 64);
    #pragma unroll
    for (int nt = 0; nt < 2; ++nt) {
      const int d = dbase + 16 * nt + l16;
      #pragma unroll
      for (int j = 0; j < 8; ++j) q[k0][nt][j] = gpk[xs[j] * DD + d];
    }
  }

  float b1v[2], b2v[2];
  #pragma unroll
  for (int nt = 0; nt < 2; ++nt) {
    b1v[nt] = b1[dbase + 16 * nt + l16];
    b2v[nt] = b2[cbase + 16 * nt + l16];
  }

  // Build all B-fragments upfront (q dies here).
  short8 bh[2][2], bl[2][2];
  #pragma unroll
  for (int k0 = 0; k0 < 2; ++k0)
    #pragma unroll
    for (int nt = 0; nt < 2; ++nt) {
      u4s8 h, l;
      #pragma unroll
      for (int p = 0; p < 4; ++p) {
        h.u[p] = perm_hi(q[k0][nt][2 * p], q[k0][nt][2 * p + 1]);
        l.u[p] = perm_lo(q[k0][nt][2 * p], q[k0][nt][2 * p + 1]);
      }
      bh[k0][nt] = h.v;
      bl[k0][nt] = l.v;
    }

  // --- P2+P3 fused, mt-outer: MFMA tile then its tanh/split/store ---
  #pragma unroll
  for (int mt = 0; mt < 4; ++mt) {
    f32x4 a1[2];
    a1[0] = (f32x4)0.0f;
    a1[1] = (f32x4)0.0f;
    #pragma unroll
    for (int k0 = 0; k0 < 2; ++k0) {
      const int sl = k0 * 32 + quad * 8;
      const int t  = mt * 16 + l16;
      short8 ah = *(const short8*)(Athi + t * WIN + sl);   // L1-resident
      short8 al = *(const short8*)(Atlo + t * WIN + sl);
      #pragma unroll
      for (int nt = 0; nt < 2; ++nt) {
        a1[nt] = __builtin_amdgcn_mfma_f32_16x16x32_bf16(ah, bh[k0][nt], a1[nt], 0, 0, 0);
        a1[nt] = __builtin_amdgcn_mfma_f32_16x16x32_bf16(ah, bl[k0][nt], a1[nt], 0, 0, 0);
        a1[nt] = __builtin_amdgcn_mfma_f32_16x16x32_bf16(al, bh[k0][nt], a1[nt], 0, 0, 0);
      }
    }
    // P3 for this mt: tanh(+b1), split, swizzled store.
    const int wsw = (quad & 2) << 3;    // row-bit3 of tl -> XOR 16 shorts
    #pragma unroll
    for (int nt = 0; nt < 2; ++nt) {
      const int ds = (dbase + 16 * nt + l16) ^ wsw;
      #pragma unroll
      for (int r = 0; r < 4; ++r) {
        const int tl = mt * 16 + quad * 4 + r;
        float hv = fast_tanh(a1[nt][r] + b1v[nt]);
        uint_t pk = split_pack(hv);
        Hhi[tl][ds] = (ushort_t)(pk >> 16);
        Hlo[tl][ds] = (ushort_t)(pk & 0xffffu);
      }
    }
  }
  __syncthreads();   // the only barrier in the hot path

  // --- P4: matmul2 MFMA, W2 prefetched 2 k0 ahead (3-ring), A direct b128 ---
  f32x4 acc2[4][2];
  #pragma unroll
  for (int mt = 0; mt < 4; ++mt)
    #pragma unroll
    for (int nt = 0; nt < 2; ++nt) acc2[mt][nt] = (f32x4)0.0f;

  short8 wh[3][2], wl[3][2];
  #pragma unroll
  for (int p = 0; p < 2; ++p) {
    const int dslp = p * 32 + quad * 8;
    #pragma unroll
    for (int nt = 0; nt < 2; ++nt) {
      const int c = cbase + 16 * nt + l16;
      wh[p][nt] = *(const short8*)(W2hi + c * DD + dslp);
      wl[p][nt] = *(const short8*)(W2lo + c * DD + dslp);
    }
  }

  #pragma unroll
  for (int k0 = 0; k0 < 8; ++k0) {
    const int cur = k0 % 3;
    if (k0 < 6) {
      const int nx   = (k0 + 2) % 3;
      const int dsln = (k0 + 2) * 32 + quad * 8;
      #pragma unroll
      for (int nt = 0; nt < 2; ++nt) {
        const int c = cbase + 16 * nt + l16;
        wh[nx][nt] = *(const short8*)(W2hi + c * DD + dsln);   // prefetch k0+2
        wl[nx][nt] = *(const short8*)(W2lo + c * DD + dsln);
      }
    }
    const int dsw = (k0 * 32 + quad * 8) ^ rsw;   // un-swizzled read col
    __builtin_amdgcn_s_setprio(1);
    #pragma unroll
    for (int mt = 0; mt < 4; ++mt) {
      const int t = mt * 16 + l16;
      short8 ah = *(const short8*)(&Hhi[t][dsw]);   // ds_read_b128
      short8 al = *(const short8*)(&Hlo[t][dsw]);
      #pragma unroll
      for (int nt = 0; nt < 2; ++nt) {
        acc2[mt][nt] = __builtin_amdgcn_mfma_f32_16x16x32_bf16(ah, wh[cur][nt], acc2[mt][nt], 0, 0, 0);
        acc2[mt][nt] = __builtin_amdgcn_mfma_f32_16x16x32_bf16(ah, wl[cur][nt], acc2[mt][nt], 0, 0, 0);
        acc2[mt][nt] = __builtin_amdgcn_mfma_f32_16x16x32_bf16(al, wh[cur][nt], acc2[mt][nt], 0, 0, 0);
      }
    }
    __builtin_amdgcn_s_setprio(0);
  }

  // --- P5: tanh(+b2) + token-sum, one atomic per (b,c) ---
  #pragma unroll
  for (int nt = 0; nt < 2; ++nt) {
    float p = 0.0f;
    #pragma unroll
    for (int mt = 0; mt < 4; ++mt)
      #pragma unroll
      for (int r = 0; r < 4; ++r)
        p += fast_tanh(acc2[mt][nt][r] + b2v[nt]);
    p += __shfl_xor(p, 16, 64);
    p += __shfl_xor(p, 32, 64);
    if (quad == 0) atomicAdd(&pool[b * DD + cbase + 16 * nt + l16], p);
  }

  // --- fused finale: last block to finish computes out[] ---
  if (done_cnt != nullptr) {
    __threadfence();                       // release our pool atomics
    if (tid == 0) {
      uint_t prev = atomicAdd(done_cnt, 1u);
      sh_last = (prev == (uint_t)(gridDim.x - 1)) ? 1 : 0;
    }
    __syncthreads();
    if (sh_last) {
      __threadfence();                     // acquire all blocks' pool writes
      if (tid < 64) {
        // 32 batches, 64 lanes each: loop batches over this single wave.
        for (int bb = 0; bb < BB; ++bb)
          final_math(pool, Wc, bc, out, bb, tid, true);
      }
    }
  }
}

// ---------------------------------------------------------------------------
// Fallback final kernel (used only when ws lacks room for the done counter).
// ---------------------------------------------------------------------------
__global__ __launch_bounds__(64) void final_kernel(
    const float* __restrict__ pool, const float* __restrict__ Wc,
    const float* __restrict__ bc, float* __restrict__ out)
{
  final_math(pool, Wc, bc, out, blockIdx.x, threadIdx.x, false);
}

extern "C" void kernel_launch(void* const* d_in, const int* in_sizes, int n_in,
                              void* d_out, int out_size, void* d_ws, size_t ws_size,
                              hipStream_t stream) {
  const int*   x   = (const int*)  d_in[0];
  const float* emb = (const float*)d_in[1];
  const float* W1  = (const float*)d_in[2];
  const float* b1  = (const float*)d_in[3];
  const float* W2  = (const float*)d_in[4];
  const float* b2  = (const float*)d_in[5];
  const float* Wc  = (const float*)d_in[6];
  const float* bc  = (const float*)d_in[7];
  float* out = (float*)d_out;
  char*  ws  = (char*)d_ws;

  const int have_cnt = (ws_size >= (size_t)WS_CNT_B + 4u) ? 1 : 0;

  prep_kernel<<<1090, 256, 0, stream>>>(emb, W1, W2, ws, have_cnt);
  main_kernel<<<BB * NW, 512, 0, stream>>>(
      x,
      (const uint_t*)  (ws + WS_GPK_B),
      (const ushort_t*)(ws + WS_ATHI_B), (const ushort_t*)(ws + WS_ATLO_B),
      b1,
      (const ushort_t*)(ws + WS_W2HI_B), (const ushort_t*)(ws + WS_W2LO_B),
      b2,
      (float*)(ws + WS_POOL_B),
      have_cnt ? (uint_t*)(ws + WS_CNT_B) : (uint_t*)nullptr,
      Wc, bc, out);
  if (!have_cnt)
    final_kernel<<<BB, 64, 0, stream>>>((const float*)(ws + WS_POOL_B), Wc, bc, out);
}

// Round 5
// 194.157 us; speedup vs baseline: 2.0580x; 2.0580x over previous
//
#include <hip/hip_runtime.h>
#include <hip/hip_bf16.h>
#include <math.h>

// Problem constants (match reference)
#define BB  32
#define SS  4096
#define VV  256
#define DD  256
#define CC  2
#define WIN 64
#define NW  64   // SS/WIN

typedef unsigned short ushort_t;
typedef unsigned int   uint_t;
typedef __attribute__((ext_vector_type(8))) short short8;    // 8 bf16 (4 VGPRs)
typedef __attribute__((ext_vector_type(4))) float f32x4;

// Workspace layout (byte offsets). Total 573440 B.
#define WS_ATHI_B 0u          // ushort Athi[64][64]   8192  (A-op layout: [t][s])
#define WS_ATLO_B 8192u       // ushort Atlo[64][64]   8192
#define WS_GPK_B  16384u      // uint   gpk[256][256]  262144 (hi<<16 | lo per elem)
#define WS_W2HI_B 278528u     // ushort W2hi[256][256] 131072
#define WS_W2LO_B 409600u     // ushort W2lo[256][256] 131072
#define WS_POOL_B 540672u     // float  pool[32][256]  32768

#define HP 264    // H plane row stride in shorts (256 + 8 pad)

__device__ __forceinline__ float fast_tanh(float v) {
  float e = __expf(2.0f * v);
  return 1.0f - __fdividef(2.0f, e + 1.0f);
}

// Truncation-based bf16 split: v ~= hi + lo with |err| <= 2^-17 * |v|.
__device__ __forceinline__ uint_t split_pack(float v) {
  uint_t b  = __float_as_uint(v);
  uint_t hi = b & 0xffff0000u;
  float  r  = v - __uint_as_float(hi);
  uint_t lo = __float_as_uint(r) >> 16;
  return hi | lo;
}

// Pack hi/lo halves of two packed u32 into bf16 pair dwords via v_perm.
__device__ __forceinline__ uint_t perm_hi(uint_t p0, uint_t p1) {
  return __builtin_amdgcn_perm(p1, p0, 0x07060302u);
}
__device__ __forceinline__ uint_t perm_lo(uint_t p0, uint_t p1) {
  return __builtin_amdgcn_perm(p1, p0, 0x05040100u);
}

union u4s8 { uint_t u[4]; short8 v; };

// ---------------------------------------------------------------------------
// Prep grid (1090 blocks): unchanged from the verified 123 us version.
// ---------------------------------------------------------------------------
__global__ __launch_bounds__(256) void prep_kernel(
    const float* __restrict__ emb, const float* __restrict__ W1,
    const float* __restrict__ W2, char* __restrict__ ws)
{
  const int blk = blockIdx.x;
  const int tid = threadIdx.x;
  ushort_t* Athi = (ushort_t*)(ws + WS_ATHI_B);
  ushort_t* Atlo = (ushort_t*)(ws + WS_ATLO_B);
  uint_t*   gpk  = (uint_t*)  (ws + WS_GPK_B);
  ushort_t* W2hi = (ushort_t*)(ws + WS_W2HI_B);
  ushort_t* W2lo = (ushort_t*)(ws + WS_W2LO_B);
  float*    pool = (float*)   (ws + WS_POOL_B);

  if (blk == 0) {
    if (tid < WIN) {
      const int s = tid;
      const float omega = 60.0f * 2.0f * 3.14159265358979323846f / 4095.0f;
      float row[WIN];
      float sum = 0.0f;
      for (int t = 0; t < WIN; ++t) {
        float e = expf(cosf(omega * (float)(s - t)));
        row[t] = e;
        sum += e;
      }
      const float inv = 1.0f / sum;
      for (int t = 0; t < WIN; ++t) {
        uint_t pk = split_pack(row[t] * inv);
        Athi[t * WIN + s] = (ushort_t)(pk >> 16);
        Atlo[t * WIN + s] = (ushort_t)(pk & 0xffffu);
      }
    }
  } else if (blk == 1) {
    for (int i = tid; i < BB * DD; i += 256) pool[i] = 0.0f;
  } else if (blk < 1026) {
    const int gv = blk - 2;            // 0..1023
    const int d0 = (gv & 15) * 16;     // 16 d-columns
    const int v0 = (gv >> 4) * 4;      // 4 v-rows
    __shared__ float er[4 * DD];       // 4 KB
    __shared__ float ps[4][16][17];    // padded partials
    *(float4*)(er + tid * 4) = *(const float4*)(emb + v0 * DD + tid * 4);
    __syncthreads();
    const int kq = tid & 15;           // k-strip: [16kq, 16kq+16)
    const int dl = tid >> 4;           // 0..15
    const int d  = d0 + dl;
    float4 wv[4];
    #pragma unroll
    for (int j = 0; j < 4; ++j)
      wv[j] = *(const float4*)(W1 + d * DD + 16 * kq + 4 * j);  // coalesced
    #pragma unroll
    for (int v = 0; v < 4; ++v) {
      float a = 0.0f;
      #pragma unroll
      for (int j = 0; j < 4; ++j) {
        float4 e = *(const float4*)(er + v * DD + 16 * kq + 4 * j);
        a += e.x * wv[j].x + e.y * wv[j].y + e.z * wv[j].z + e.w * wv[j].w;
      }
      ps[v][dl][kq] = a;
    }
    __syncthreads();
    if (tid < 64) {
      const int v = tid >> 4, dr = tid & 15;
      float s = 0.0f;
      #pragma unroll
      for (int k = 0; k < 16; ++k) s += ps[v][dr][k];
      gpk[(v0 + v) * DD + d0 + dr] = split_pack(s);
    }
  } else {
    const int c0 = (blk - 1026) * 4;
    #pragma unroll
    for (int i = 0; i < 4; ++i) {
      const int c = c0 + i;
      uint_t pk = split_pack(W2[c * DD + tid]);
      W2hi[c * DD + tid] = (ushort_t)(pk >> 16);
      W2lo[c * DD + tid] = (ushort_t)(pk & 0xffffu);
    }
  }
}

// ---------------------------------------------------------------------------
// Main fused kernel — round-3 verified shape (512 thr, 2 blk/CU, no spill),
// now processing TWO consecutive windows per block (grid 1024):
//   window 0: P2..P5 exactly as verified; during P4's k0==0, issue window 1's
//   gpk gather (32 L2 loads) -> its ~400-900 cy latency hides under the
//   remaining ~7 k0 steps of MFMA instead of being exposed at a block start.
// Register budget at P4 peak (pre-counted, round-1/2 lesson): acc2 32 +
// W2 dbuf 32 + q-next 32 + scalars ~20 ~= 118 <= 128 at 4 waves/SIMD.
// Tripwires: WRITE_SIZE must stay ~2 MB (spill), VGPR_Count <= ~110.
// Per-window op order, barriers, and atomic statements are bit-identical;
// one extra barrier per pair protects H reuse between the windows.
// ---------------------------------------------------------------------------
__global__ __launch_bounds__(512, 4) void main_kernel(
    const int*      __restrict__ x,    const uint_t* __restrict__ gpk,
    const ushort_t* __restrict__ Athi, const ushort_t* __restrict__ Atlo,
    const float*    __restrict__ b1,
    const ushort_t* __restrict__ W2hi, const ushort_t* __restrict__ W2lo,
    const float*    __restrict__ b2,   float* __restrict__ pool)
{
  __shared__ ushort_t Hhi[WIN][HP];   // 33792 B
  __shared__ ushort_t Hlo[WIN][HP];   // 33792 B (total 67584 -> 2 blocks/CU)

  const int tid  = threadIdx.x;
  const int lane = tid & 63;
  const int w    = tid >> 6;       // 0..7
  const int quad = lane >> 4;
  const int l16  = lane & 15;
  const int b  = blockIdx.x >> 5;        // batch
  const int n0 = (blockIdx.x & 31) * 2;  // first of 2 windows

  const int dbase = 32 * w;        // this wave's d-slice (P2) == c-slice (P4)
  const int cbase = dbase;
  const int rsw   = (l16 & 8) << 1;   // P4 read un-swizzle (16 shorts)

  // --- P1 (window 0): gather issued first; window-1 token ids loaded too ---
  const int xvA = x[b * SS + n0 * WIN + lane];
  const int xvB = x[b * SS + (n0 + 1) * WIN + lane];
  uint_t qA[2][2][8], qB[2][2][8];
  #pragma unroll
  for (int k0 = 0; k0 < 2; ++k0) {
    const int sl = k0 * 32 + quad * 8;
    int xs[8];
    #pragma unroll
    for (int j = 0; j < 8; ++j) xs[j] = __shfl(xvA, sl + j, 64);
    #pragma unroll
    for (int nt = 0; nt < 2; ++nt) {
      const int d = dbase + 16 * nt + l16;
      #pragma unroll
      for (int j = 0; j < 8; ++j) qA[k0][nt][j] = gpk[xs[j] * DD + d];
    }
  }

  float b1v[2], b2v[2];
  #pragma unroll
  for (int nt = 0; nt < 2; ++nt) {
    b1v[nt] = b1[dbase + 16 * nt + l16];
    b2v[nt] = b2[cbase + 16 * nt + l16];
  }

  #pragma unroll
  for (int iw = 0; iw < 2; ++iw) {
    const bool first = (iw == 0);

    // Build B-fragments from this window's gather regs (they die here).
    short8 bh[2][2], bl[2][2];
    #pragma unroll
    for (int k0 = 0; k0 < 2; ++k0)
      #pragma unroll
      for (int nt = 0; nt < 2; ++nt) {
        u4s8 h, l;
        #pragma unroll
        for (int p = 0; p < 4; ++p) {
          const uint_t p0 = first ? qA[k0][nt][2 * p]     : qB[k0][nt][2 * p];
          const uint_t p1 = first ? qA[k0][nt][2 * p + 1] : qB[k0][nt][2 * p + 1];
          h.u[p] = perm_hi(p0, p1);
          l.u[p] = perm_lo(p0, p1);
        }
        bh[k0][nt] = h.v;
        bl[k0][nt] = l.v;
      }

    // --- P2+P3 fused, mt-outer: MFMA tile then its tanh/split/store ---
    #pragma unroll
    for (int mt = 0; mt < 4; ++mt) {
      f32x4 a1[2];
      a1[0] = (f32x4)0.0f;
      a1[1] = (f32x4)0.0f;
      #pragma unroll
      for (int k0 = 0; k0 < 2; ++k0) {
        const int sl = k0 * 32 + quad * 8;
        const int t  = mt * 16 + l16;
        short8 ah = *(const short8*)(Athi + t * WIN + sl);   // L1-resident
        short8 al = *(const short8*)(Atlo + t * WIN + sl);
        #pragma unroll
        for (int nt = 0; nt < 2; ++nt) {
          a1[nt] = __builtin_amdgcn_mfma_f32_16x16x32_bf16(ah, bh[k0][nt], a1[nt], 0, 0, 0);
          a1[nt] = __builtin_amdgcn_mfma_f32_16x16x32_bf16(ah, bl[k0][nt], a1[nt], 0, 0, 0);
          a1[nt] = __builtin_amdgcn_mfma_f32_16x16x32_bf16(al, bh[k0][nt], a1[nt], 0, 0, 0);
        }
      }
      // P3 for this mt: tanh(+b1), split, swizzled store.
      const int wsw = (quad & 2) << 3;    // row-bit3 of tl -> XOR 16 shorts
      #pragma unroll
      for (int nt = 0; nt < 2; ++nt) {
        const int ds = (dbase + 16 * nt + l16) ^ wsw;
        #pragma unroll
        for (int r = 0; r < 4; ++r) {
          const int tl = mt * 16 + quad * 4 + r;
          float hv = fast_tanh(a1[nt][r] + b1v[nt]);
          uint_t pk = split_pack(hv);
          Hhi[tl][ds] = (ushort_t)(pk >> 16);
          Hlo[tl][ds] = (ushort_t)(pk & 0xffffu);
        }
      }
    }
    __syncthreads();   // H(window) complete

    // --- P4: matmul2 MFMA, W2 double-buffered, A-frags direct b128 ---
    f32x4 acc2[4][2];
    #pragma unroll
    for (int mt = 0; mt < 4; ++mt)
      #pragma unroll
      for (int nt = 0; nt < 2; ++nt) acc2[mt][nt] = (f32x4)0.0f;

    short8 wh[2][2], wl[2][2];
    {
      const int dsl0 = quad * 8;
      #pragma unroll
      for (int nt = 0; nt < 2; ++nt) {
        const int c = cbase + 16 * nt + l16;
        wh[0][nt] = *(const short8*)(W2hi + c * DD + dsl0);
        wl[0][nt] = *(const short8*)(W2lo + c * DD + dsl0);
      }
    }

    #pragma unroll 2
    for (int k0 = 0; k0 < 8; ++k0) {
      const int cur = k0 & 1, nxt = cur ^ 1;
      const int dsl = k0 * 32 + quad * 8;
      if (k0 < 7) {
        const int dsln = dsl + 32;
        #pragma unroll
        for (int nt = 0; nt < 2; ++nt) {
          const int c = cbase + 16 * nt + l16;
          wh[nxt][nt] = *(const short8*)(W2hi + c * DD + dsln);   // prefetch k0+1
          wl[nxt][nt] = *(const short8*)(W2lo + c * DD + dsln);
        }
      }
      // Window-1 gather, issued once, early in window-0's P4: ~7 k0 steps of
      // MFMA cover its L2 latency. xvB loaded at block start (no vmem dep).
      if (first && k0 == 0) {
        #pragma unroll
        for (int kk = 0; kk < 2; ++kk) {
          const int sl2 = kk * 32 + quad * 8;
          int xs2[8];
          #pragma unroll
          for (int j = 0; j < 8; ++j) xs2[j] = __shfl(xvB, sl2 + j, 64);
          #pragma unroll
          for (int nt = 0; nt < 2; ++nt) {
            const int d = dbase + 16 * nt + l16;
            #pragma unroll
            for (int j = 0; j < 8; ++j) qB[kk][nt][j] = gpk[xs2[j] * DD + d];
          }
        }
      }
      const int dsw = dsl ^ rsw;          // un-swizzle for row t = mt*16 + l16
      __builtin_amdgcn_s_setprio(1);
      #pragma unroll
      for (int mt = 0; mt < 4; ++mt) {
        const int t = mt * 16 + l16;
        short8 ah = *(const short8*)(&Hhi[t][dsw]);   // ds_read_b128
        short8 al = *(const short8*)(&Hlo[t][dsw]);
        #pragma unroll
        for (int nt = 0; nt < 2; ++nt) {
          acc2[mt][nt] = __builtin_amdgcn_mfma_f32_16x16x32_bf16(ah, wh[cur][nt], acc2[mt][nt], 0, 0, 0);
          acc2[mt][nt] = __builtin_amdgcn_mfma_f32_16x16x32_bf16(ah, wl[cur][nt], acc2[mt][nt], 0, 0, 0);
          acc2[mt][nt] = __builtin_amdgcn_mfma_f32_16x16x32_bf16(al, wh[cur][nt], acc2[mt][nt], 0, 0, 0);
        }
      }
      __builtin_amdgcn_s_setprio(0);
    }

    // --- P5: tanh(+b2) + token-sum, one atomic per (b,c) ---
    #pragma unroll
    for (int nt = 0; nt < 2; ++nt) {
      float p = 0.0f;
      #pragma unroll
      for (int mt = 0; mt < 4; ++mt)
        #pragma unroll
        for (int r = 0; r < 4; ++r)
          p += fast_tanh(acc2[mt][nt][r] + b2v[nt]);
      p += __shfl_xor(p, 16, 64);
      p += __shfl_xor(p, 32, 64);
      if (quad == 0) atomicAdd(&pool[b * DD + cbase + 16 * nt + l16], p);
    }

    if (first) __syncthreads();   // all P4 reads done before window-1's P3
  }
}

// ---------------------------------------------------------------------------
// Final: out[b,c] = (pool[b,:] / S) . Wc[c,:] + bc[c].  One block per b.
// ---------------------------------------------------------------------------
__global__ __launch_bounds__(64) void final_kernel(
    const float* __restrict__ pool, const float* __restrict__ Wc,
    const float* __restrict__ bc, float* __restrict__ out)
{
  const int b = blockIdx.x;
  const int t = threadIdx.x;
  float p0 = 0.0f, p1 = 0.0f;
  #pragma unroll
  for (int j = 0; j < 4; ++j) {
    float pv = pool[b * DD + t + 64 * j];
    p0 += pv * Wc[t + 64 * j];
    p1 += pv * Wc[DD + t + 64 * j];
  }
  #pragma unroll
  for (int off = 32; off; off >>= 1) {
    p0 += __shfl_xor(p0, off, 64);
    p1 += __shfl_xor(p1, off, 64);
  }
  if (t == 0) {
    out[b * CC + 0] = p0 * (1.0f / SS) + bc[0];
    out[b * CC + 1] = p1 * (1.0f / SS) + bc[1];
  }
}

extern "C" void kernel_launch(void* const* d_in, const int* in_sizes, int n_in,
                              void* d_out, int out_size, void* d_ws, size_t ws_size,
                              hipStream_t stream) {
  const int*   x   = (const int*)  d_in[0];
  const float* emb = (const float*)d_in[1];
  const float* W1  = (const float*)d_in[2];
  const float* b1  = (const float*)d_in[3];
  const float* W2  = (const float*)d_in[4];
  const float* b2  = (const float*)d_in[5];
  const float* Wc  = (const float*)d_in[6];
  const float* bc  = (const float*)d_in[7];
  float* out = (float*)d_out;
  char*  ws  = (char*)d_ws;

  prep_kernel<<<1090, 256, 0, stream>>>(emb, W1, W2, ws);
  main_kernel<<<BB * NW / 2, 512, 0, stream>>>(
      x,
      (const uint_t*)  (ws + WS_GPK_B),
      (const ushort_t*)(ws + WS_ATHI_B), (const ushort_t*)(ws + WS_ATLO_B),
      b1,
      (const ushort_t*)(ws + WS_W2HI_B), (const ushort_t*)(ws + WS_W2LO_B),
      b2,
      (float*)(ws + WS_POOL_B));
  final_kernel<<<BB, 64, 0, stream>>>((const float*)(ws + WS_POOL_B), Wc, bc, out);
}

// Round 6
// 176.510 us; speedup vs baseline: 2.2638x; 1.1000x over previous
//
#include <hip/hip_runtime.h>
#include <hip/hip_bf16.h>
#include <math.h>

// Problem constants (match reference)
#define BB  32
#define SS  4096
#define VV  256
#define DD  256
#define CC  2
#define WIN 64
#define NW  64   // SS/WIN

typedef unsigned short ushort_t;
typedef unsigned int   uint_t;
typedef __attribute__((ext_vector_type(8))) short short8;    // 8 bf16 (4 VGPRs)
typedef __attribute__((ext_vector_type(4))) float f32x4;

// Workspace layout (byte offsets). Total 573440 B.
#define WS_ATHI_B 0u          // ushort Athi[64][64]   8192  (A-op layout: [t][s])
#define WS_ATLO_B 8192u       // ushort Atlo[64][64]   8192
#define WS_GPK_B  16384u      // uint   gpk[256][256]  262144 (hi<<16 | lo per elem)
#define WS_W2HI_B 278528u     // ushort W2hi[256][256] 131072
#define WS_W2LO_B 409600u     // ushort W2lo[256][256] 131072
#define WS_POOL_B 540672u     // float  pool[32][256]  32768

#define HP 264    // H plane row stride in shorts (256 + 8 pad)

__device__ __forceinline__ float fast_tanh(float v) {
  float e = __expf(2.0f * v);
  return 1.0f - __fdividef(2.0f, e + 1.0f);
}

// Truncation-based bf16 split: v ~= hi + lo with |err| <= 2^-17 * |v|.
__device__ __forceinline__ uint_t split_pack(float v) {
  uint_t b  = __float_as_uint(v);
  uint_t hi = b & 0xffff0000u;
  float  r  = v - __uint_as_float(hi);
  uint_t lo = __float_as_uint(r) >> 16;
  return hi | lo;
}

// Pack hi/lo halves of two packed u32 into bf16 pair dwords via v_perm.
__device__ __forceinline__ uint_t perm_hi(uint_t p0, uint_t p1) {
  return __builtin_amdgcn_perm(p1, p0, 0x07060302u);
}
__device__ __forceinline__ uint_t perm_lo(uint_t p0, uint_t p1) {
  return __builtin_amdgcn_perm(p1, p0, 0x05040100u);
}

union u4s8 { uint_t u[4]; short8 v; };

// ---------------------------------------------------------------------------
// Prep grid (1090 blocks): unchanged from the verified 123 us version.
// ---------------------------------------------------------------------------
__global__ __launch_bounds__(256) void prep_kernel(
    const float* __restrict__ emb, const float* __restrict__ W1,
    const float* __restrict__ W2, char* __restrict__ ws)
{
  const int blk = blockIdx.x;
  const int tid = threadIdx.x;
  ushort_t* Athi = (ushort_t*)(ws + WS_ATHI_B);
  ushort_t* Atlo = (ushort_t*)(ws + WS_ATLO_B);
  uint_t*   gpk  = (uint_t*)  (ws + WS_GPK_B);
  ushort_t* W2hi = (ushort_t*)(ws + WS_W2HI_B);
  ushort_t* W2lo = (ushort_t*)(ws + WS_W2LO_B);
  float*    pool = (float*)   (ws + WS_POOL_B);

  if (blk == 0) {
    if (tid < WIN) {
      const int s = tid;
      const float omega = 60.0f * 2.0f * 3.14159265358979323846f / 4095.0f;
      float row[WIN];
      float sum = 0.0f;
      for (int t = 0; t < WIN; ++t) {
        float e = expf(cosf(omega * (float)(s - t)));
        row[t] = e;
        sum += e;
      }
      const float inv = 1.0f / sum;
      for (int t = 0; t < WIN; ++t) {
        uint_t pk = split_pack(row[t] * inv);
        Athi[t * WIN + s] = (ushort_t)(pk >> 16);
        Atlo[t * WIN + s] = (ushort_t)(pk & 0xffffu);
      }
    }
  } else if (blk == 1) {
    for (int i = tid; i < BB * DD; i += 256) pool[i] = 0.0f;
  } else if (blk < 1026) {
    const int gv = blk - 2;            // 0..1023
    const int d0 = (gv & 15) * 16;     // 16 d-columns
    const int v0 = (gv >> 4) * 4;      // 4 v-rows
    __shared__ float er[4 * DD];       // 4 KB
    __shared__ float ps[4][16][17];    // padded partials
    *(float4*)(er + tid * 4) = *(const float4*)(emb + v0 * DD + tid * 4);
    __syncthreads();
    const int kq = tid & 15;           // k-strip: [16kq, 16kq+16)
    const int dl = tid >> 4;           // 0..15
    const int d  = d0 + dl;
    float4 wv[4];
    #pragma unroll
    for (int j = 0; j < 4; ++j)
      wv[j] = *(const float4*)(W1 + d * DD + 16 * kq + 4 * j);  // coalesced
    #pragma unroll
    for (int v = 0; v < 4; ++v) {
      float a = 0.0f;
      #pragma unroll
      for (int j = 0; j < 4; ++j) {
        float4 e = *(const float4*)(er + v * DD + 16 * kq + 4 * j);
        a += e.x * wv[j].x + e.y * wv[j].y + e.z * wv[j].z + e.w * wv[j].w;
      }
      ps[v][dl][kq] = a;
    }
    __syncthreads();
    if (tid < 64) {
      const int v = tid >> 4, dr = tid & 15;
      float s = 0.0f;
      #pragma unroll
      for (int k = 0; k < 16; ++k) s += ps[v][dr][k];
      gpk[(v0 + v) * DD + d0 + dr] = split_pack(s);
    }
  } else {
    const int c0 = (blk - 1026) * 4;
    #pragma unroll
    for (int i = 0; i < 4; ++i) {
      const int c = c0 + i;
      uint_t pk = split_pack(W2[c * DD + tid]);
      W2hi[c * DD + tid] = (ushort_t)(pk >> 16);
      W2lo[c * DD + tid] = (ushort_t)(pk & 0xffffu);
    }
  }
}

// ---------------------------------------------------------------------------
// Main fused kernel — round-0 verified shape (one block per (b,n), 512 thr,
// 2 blk/CU, 128-reg envelope, no spill) with the phase-lock broken:
//
// P4's k0-step consumes H[:, 32*k0 .. 32*k0+32) == exactly wave k0's P3
// output. So the full __syncthreads() between P3 and P4 is replaced by 8
// per-slice LDS ready flags (release after P3, acquire-poll before use) and
// each wave walks k0 in rotated order starting at ITS OWN slice (w, w+1, ..).
// Effect: a wave enters P4 MFMA right after its own P3 with zero wait;
// leading waves' MFMAs overlap trailing waves' P3 VALU (MfmaUtil 22% +
// VALUBusy 40% never overlapped before); no max-of-8 convoy; the two
// resident blocks de-correlate; setprio now has role-diverse waves (T5's
// regime). Register cost ~0 (index rotation). acc2's k-order rotates per
// wave -> absmax ~1e-6 fp reorder instead of 0.0.
// Tripwires: WRITE_SIZE ~2 MB, VGPR ~64 (spill = revert).
// ---------------------------------------------------------------------------
__global__ __launch_bounds__(512, 4) void main_kernel(
    const int*      __restrict__ x,    const uint_t* __restrict__ gpk,
    const ushort_t* __restrict__ Athi, const ushort_t* __restrict__ Atlo,
    const float*    __restrict__ b1,
    const ushort_t* __restrict__ W2hi, const ushort_t* __restrict__ W2lo,
    const float*    __restrict__ b2,   float* __restrict__ pool)
{
  __shared__ ushort_t Hhi[WIN][HP];   // 33792 B
  __shared__ ushort_t Hlo[WIN][HP];   // 33792 B (total 67616 -> 2 blocks/CU)
  __shared__ int ready[8];            // per-wave d-slice published flags

  const int tid  = threadIdx.x;
  const int lane = tid & 63;
  const int w    = tid >> 6;       // 0..7
  const int quad = lane >> 4;
  const int l16  = lane & 15;
  const int b = blockIdx.x >> 6;
  const int n = blockIdx.x & 63;

  const int dbase = 32 * w;        // this wave's d-slice (P2) == c-slice (P4)
  const int cbase = dbase;
  const int rsw   = (l16 & 8) << 1;   // P4 read un-swizzle (16 shorts)

  if (tid < 8) ready[tid] = 0;

  // --- P1: gather (packed u32), issued first so latency overlaps setup ---
  const int xv = x[b * SS + n * WIN + lane];
  uint_t q[2][2][8];
  #pragma unroll
  for (int k0 = 0; k0 < 2; ++k0) {
    const int sl = k0 * 32 + quad * 8;
    int xs[8];
    #pragma unroll
    for (int j = 0; j < 8; ++j) xs[j] = __shfl(xv, sl + j, 64);
    #pragma unroll
    for (int nt = 0; nt < 2; ++nt) {
      const int d = dbase + 16 * nt + l16;
      #pragma unroll
      for (int j = 0; j < 8; ++j) q[k0][nt][j] = gpk[xs[j] * DD + d];
    }
  }

  float b1v[2], b2v[2];
  #pragma unroll
  for (int nt = 0; nt < 2; ++nt) {
    b1v[nt] = b1[dbase + 16 * nt + l16];
    b2v[nt] = b2[cbase + 16 * nt + l16];
  }

  __syncthreads();   // flags zeroed before any wave can publish

  // Build all B-fragments upfront (q dies here).
  short8 bh[2][2], bl[2][2];
  #pragma unroll
  for (int k0 = 0; k0 < 2; ++k0)
    #pragma unroll
    for (int nt = 0; nt < 2; ++nt) {
      u4s8 h, l;
      #pragma unroll
      for (int p = 0; p < 4; ++p) {
        h.u[p] = perm_hi(q[k0][nt][2 * p], q[k0][nt][2 * p + 1]);
        l.u[p] = perm_lo(q[k0][nt][2 * p], q[k0][nt][2 * p + 1]);
      }
      bh[k0][nt] = h.v;
      bl[k0][nt] = l.v;
    }

  // --- P2+P3 fused, mt-outer: MFMA tile then its tanh/split/store ---
  #pragma unroll
  for (int mt = 0; mt < 4; ++mt) {
    f32x4 a1[2];
    a1[0] = (f32x4)0.0f;
    a1[1] = (f32x4)0.0f;
    #pragma unroll
    for (int k0 = 0; k0 < 2; ++k0) {
      const int sl = k0 * 32 + quad * 8;
      const int t  = mt * 16 + l16;
      short8 ah = *(const short8*)(Athi + t * WIN + sl);   // L1-resident
      short8 al = *(const short8*)(Atlo + t * WIN + sl);
      #pragma unroll
      for (int nt = 0; nt < 2; ++nt) {
        a1[nt] = __builtin_amdgcn_mfma_f32_16x16x32_bf16(ah, bh[k0][nt], a1[nt], 0, 0, 0);
        a1[nt] = __builtin_amdgcn_mfma_f32_16x16x32_bf16(ah, bl[k0][nt], a1[nt], 0, 0, 0);
        a1[nt] = __builtin_amdgcn_mfma_f32_16x16x32_bf16(al, bh[k0][nt], a1[nt], 0, 0, 0);
      }
    }
    // P3 for this mt: tanh(+b1), split, swizzled store.
    const int wsw = (quad & 2) << 3;    // row-bit3 of tl -> XOR 16 shorts
    #pragma unroll
    for (int nt = 0; nt < 2; ++nt) {
      const int ds = (dbase + 16 * nt + l16) ^ wsw;
      #pragma unroll
      for (int r = 0; r < 4; ++r) {
        const int tl = mt * 16 + quad * 4 + r;
        float hv = fast_tanh(a1[nt][r] + b1v[nt]);
        uint_t pk = split_pack(hv);
        Hhi[tl][ds] = (ushort_t)(pk >> 16);
        Hlo[tl][ds] = (ushort_t)(pk & 0xffffu);
      }
    }
  }

  // Publish this wave's d-slice (release: drains the ds_writes first).
  __hip_atomic_store(&ready[w], 1, __ATOMIC_RELEASE, __HIP_MEMORY_SCOPE_WORKGROUP);

  // --- P4: matmul2 MFMA, rotated k0 (start at own slice), W2 dbuf ring ---
  f32x4 acc2[4][2];
  #pragma unroll
  for (int mt = 0; mt < 4; ++mt)
    #pragma unroll
    for (int nt = 0; nt < 2; ++nt) acc2[mt][nt] = (f32x4)0.0f;

  short8 wh[2][2], wl[2][2];
  {
    const int dsl0 = w * 32 + quad * 8;   // first k0 = own slice
    #pragma unroll
    for (int nt = 0; nt < 2; ++nt) {
      const int c = cbase + 16 * nt + l16;
      wh[0][nt] = *(const short8*)(W2hi + c * DD + dsl0);
      wl[0][nt] = *(const short8*)(W2lo + c * DD + dsl0);
    }
  }

  #pragma unroll 2
  for (int kk = 0; kk < 8; ++kk) {
    const int k0  = (w + kk) & 7;
    const int cur = kk & 1, nxt = cur ^ 1;
    if (kk < 7) {
      const int dsln = ((w + kk + 1) & 7) * 32 + quad * 8;
      #pragma unroll
      for (int nt = 0; nt < 2; ++nt) {
        const int c = cbase + 16 * nt + l16;
        wh[nxt][nt] = *(const short8*)(W2hi + c * DD + dsln);   // prefetch kk+1
        wl[nxt][nt] = *(const short8*)(W2lo + c * DD + dsln);
      }
    }
    // Wait for slice k0's producer (kk==0 -> own slice, succeeds instantly).
    while (__hip_atomic_load(&ready[k0], __ATOMIC_ACQUIRE,
                             __HIP_MEMORY_SCOPE_WORKGROUP) == 0) { }
    const int dsw = (k0 * 32 + quad * 8) ^ rsw;   // un-swizzled read col
    __builtin_amdgcn_s_setprio(1);
    #pragma unroll
    for (int mt = 0; mt < 4; ++mt) {
      const int t = mt * 16 + l16;
      short8 ah = *(const short8*)(&Hhi[t][dsw]);   // ds_read_b128
      short8 al = *(const short8*)(&Hlo[t][dsw]);
      #pragma unroll
      for (int nt = 0; nt < 2; ++nt) {
        acc2[mt][nt] = __builtin_amdgcn_mfma_f32_16x16x32_bf16(ah, wh[cur][nt], acc2[mt][nt], 0, 0, 0);
        acc2[mt][nt] = __builtin_amdgcn_mfma_f32_16x16x32_bf16(ah, wl[cur][nt], acc2[mt][nt], 0, 0, 0);
        acc2[mt][nt] = __builtin_amdgcn_mfma_f32_16x16x32_bf16(al, wh[cur][nt], acc2[mt][nt], 0, 0, 0);
      }
    }
    __builtin_amdgcn_s_setprio(0);
  }

  // --- P5: tanh(+b2) + token-sum, one atomic per (b,c) ---
  #pragma unroll
  for (int nt = 0; nt < 2; ++nt) {
    float p = 0.0f;
    #pragma unroll
    for (int mt = 0; mt < 4; ++mt)
      #pragma unroll
      for (int r = 0; r < 4; ++r)
        p += fast_tanh(acc2[mt][nt][r] + b2v[nt]);
    p += __shfl_xor(p, 16, 64);
    p += __shfl_xor(p, 32, 64);
    if (quad == 0) atomicAdd(&pool[b * DD + cbase + 16 * nt + l16], p);
  }
}

// ---------------------------------------------------------------------------
// Final: out[b,c] = (pool[b,:] / S) . Wc[c,:] + bc[c].  One block per b.
// ---------------------------------------------------------------------------
__global__ __launch_bounds__(64) void final_kernel(
    const float* __restrict__ pool, const float* __restrict__ Wc,
    const float* __restrict__ bc, float* __restrict__ out)
{
  const int b = blockIdx.x;
  const int t = threadIdx.x;
  float p0 = 0.0f, p1 = 0.0f;
  #pragma unroll
  for (int j = 0; j < 4; ++j) {
    float pv = pool[b * DD + t + 64 * j];
    p0 += pv * Wc[t + 64 * j];
    p1 += pv * Wc[DD + t + 64 * j];
  }
  #pragma unroll
  for (int off = 32; off; off >>= 1) {
    p0 += __shfl_xor(p0, off, 64);
    p1 += __shfl_xor(p1, off, 64);
  }
  if (t == 0) {
    out[b * CC + 0] = p0 * (1.0f / SS) + bc[0];
    out[b * CC + 1] = p1 * (1.0f / SS) + bc[1];
  }
}

extern "C" void kernel_launch(void* const* d_in, const int* in_sizes, int n_in,
                              void* d_out, int out_size, void* d_ws, size_t ws_size,
                              hipStream_t stream) {
  const int*   x   = (const int*)  d_in[0];
  const float* emb = (const float*)d_in[1];
  const float* W1  = (const float*)d_in[2];
  const float* b1  = (const float*)d_in[3];
  const float* W2  = (const float*)d_in[4];
  const float* b2  = (const float*)d_in[5];
  const float* Wc  = (const float*)d_in[6];
  const float* bc  = (const float*)d_in[7];
  float* out = (float*)d_out;
  char*  ws  = (char*)d_ws;

  prep_kernel<<<1090, 256, 0, stream>>>(emb, W1, W2, ws);
  main_kernel<<<BB * NW, 512, 0, stream>>>(
      x,
      (const uint_t*)  (ws + WS_GPK_B),
      (const ushort_t*)(ws + WS_ATHI_B), (const ushort_t*)(ws + WS_ATLO_B),
      b1,
      (const ushort_t*)(ws + WS_W2HI_B), (const ushort_t*)(ws + WS_W2LO_B),
      b2,
      (float*)(ws + WS_POOL_B));
  final_kernel<<<BB, 64, 0, stream>>>((const float*)(ws + WS_POOL_B), Wc, bc, out);
}

// Round 7
// 134.569 us; speedup vs baseline: 2.9694x; 1.3117x over previous
//
#include <hip/hip_runtime.h>
#include <hip/hip_bf16.h>
#include <math.h>

// Problem constants (match reference)
#define BB  32
#define SS  4096
#define VV  256
#define DD  256
#define CC  2
#define WIN 64
#define NW  64   // SS/WIN

typedef unsigned short ushort_t;
typedef unsigned int   uint_t;
typedef _Float16 half_t;
typedef __attribute__((ext_vector_type(8))) _Float16 half8;   // 8 f16 (4 VGPRs)
typedef __attribute__((ext_vector_type(4))) float f32x4;

// Workspace layout (byte offsets). Total 303104 B (fits prior 573440 ws).
#define WS_A16_B  0u          // half A16[64][64]     8192  (A-op layout: [t][s])
#define WS_G16_B  8192u       // half g16[256][256]   131072
#define WS_W216_B 139264u     // half W216[256][256]  131072
#define WS_POOL_B 270336u     // float pool[32][256]  32768

#define HP 264    // H plane row stride in halfs (256 + 8 pad; row = 528 B = 33*16)

__device__ __forceinline__ float fast_tanh(float v) {
  float e = __expf(2.0f * v);
  return 1.0f - __fdividef(2.0f, e + 1.0f);
}

union u4h8 { uint_t u[4]; half8 v; };

// ---------------------------------------------------------------------------
// Prep grid (1090 blocks): same structure as the verified kernel, but all
// planes are single fp16 (RNE via _Float16 cast): A, g = emb@W1^T, W2.
// ---------------------------------------------------------------------------
__global__ __launch_bounds__(256) void prep_kernel(
    const float* __restrict__ emb, const float* __restrict__ W1,
    const float* __restrict__ W2, char* __restrict__ ws)
{
  const int blk = blockIdx.x;
  const int tid = threadIdx.x;
  half_t* A16  = (half_t*)(ws + WS_A16_B);
  half_t* g16  = (half_t*)(ws + WS_G16_B);
  half_t* W216 = (half_t*)(ws + WS_W216_B);
  float*  pool = (float*) (ws + WS_POOL_B);

  if (blk == 0) {
    if (tid < WIN) {
      const int s = tid;
      const float omega = 60.0f * 2.0f * 3.14159265358979323846f / 4095.0f;
      float row[WIN];
      float sum = 0.0f;
      for (int t = 0; t < WIN; ++t) {
        float e = expf(cosf(omega * (float)(s - t)));
        row[t] = e;
        sum += e;
      }
      const float inv = 1.0f / sum;
      for (int t = 0; t < WIN; ++t)
        A16[t * WIN + s] = (half_t)(row[t] * inv);
    }
  } else if (blk == 1) {
    for (int i = tid; i < BB * DD; i += 256) pool[i] = 0.0f;
  } else if (blk < 1026) {
    const int gv = blk - 2;            // 0..1023
    const int d0 = (gv & 15) * 16;     // 16 d-columns
    const int v0 = (gv >> 4) * 4;      // 4 v-rows
    __shared__ float er[4 * DD];       // 4 KB
    __shared__ float ps[4][16][17];    // padded partials
    *(float4*)(er + tid * 4) = *(const float4*)(emb + v0 * DD + tid * 4);
    __syncthreads();
    const int kq = tid & 15;           // k-strip: [16kq, 16kq+16)
    const int dl = tid >> 4;           // 0..15
    const int d  = d0 + dl;
    float4 wv[4];
    #pragma unroll
    for (int j = 0; j < 4; ++j)
      wv[j] = *(const float4*)(W1 + d * DD + 16 * kq + 4 * j);  // coalesced
    #pragma unroll
    for (int v = 0; v < 4; ++v) {
      float a = 0.0f;
      #pragma unroll
      for (int j = 0; j < 4; ++j) {
        float4 e = *(const float4*)(er + v * DD + 16 * kq + 4 * j);
        a += e.x * wv[j].x + e.y * wv[j].y + e.z * wv[j].z + e.w * wv[j].w;
      }
      ps[v][dl][kq] = a;
    }
    __syncthreads();
    if (tid < 64) {
      const int v = tid >> 4, dr = tid & 15;
      float s = 0.0f;
      #pragma unroll
      for (int k = 0; k < 16; ++k) s += ps[v][dr][k];
      g16[(v0 + v) * DD + d0 + dr] = (half_t)s;
    }
  } else {
    const int c0 = (blk - 1026) * 4;
    #pragma unroll
    for (int i = 0; i < 4; ++i) {
      const int c = c0 + i;
      W216[c * DD + tid] = (half_t)W2[c * DD + tid];
    }
  }
}

// ---------------------------------------------------------------------------
// Main fused kernel — round-6 WINNING structure (one block per (b,n), 512
// thr, per-slice ready flags + rotated k0 + setprio, no P3->P4 barrier),
// with the precision scheme changed from 3-term bf16-split to SINGLE fp16:
//   * one A plane, one g plane, one W2 plane, one H LDS plane
//   * P2: 1 MFMA per (mt,nt,k0)  (was 3);  P4: 1 per (mt,nt,kk)  (was 3)
//   * P3: one v_cvt_f16_f32 + one b16 store per element (was 4-op split + 2)
//   * gather: ushort loads (half bytes), frag pack = 1 lshl_or per pair
// Error budget: fp16 product err ~2^-12 -> pre-activation ~1e-4 ->
// token-mean + Wc dot -> ~1e-4 final. EXPERIMENT: if passed=false, fp16 is
// out of tolerance and we revert to the round-6 bf16-split kernel.
// Tripwires: WRITE_SIZE ~2 MB, VGPR <= 64.
// ---------------------------------------------------------------------------
__global__ __launch_bounds__(512, 4) void main_kernel(
    const int*      __restrict__ x,    const ushort_t* __restrict__ g16u,
    const half_t*   __restrict__ A16,  const float*    __restrict__ b1,
    const half_t*   __restrict__ W216, const float*    __restrict__ b2,
    float* __restrict__ pool)
{
  __shared__ half_t H16[WIN][HP];     // 33792 B -> LDS no longer the cap
  __shared__ int ready[8];            // per-wave d-slice published flags

  const int tid  = threadIdx.x;
  const int lane = tid & 63;
  const int w    = tid >> 6;       // 0..7
  const int quad = lane >> 4;
  const int l16  = lane & 15;
  const int b = blockIdx.x >> 6;
  const int n = blockIdx.x & 63;

  const int dbase = 32 * w;        // this wave's d-slice (P2) == c-slice (P4)
  const int cbase = dbase;
  const int rsw   = (l16 & 8) << 1;   // P4 read un-swizzle (16 halfs)

  if (tid < 8) ready[tid] = 0;

  // --- P1: gather (fp16, ushort loads), issued first to overlap setup ---
  const int xv = x[b * SS + n * WIN + lane];
  uint_t q[2][2][8];
  #pragma unroll
  for (int k0 = 0; k0 < 2; ++k0) {
    const int sl = k0 * 32 + quad * 8;
    int xs[8];
    #pragma unroll
    for (int j = 0; j < 8; ++j) xs[j] = __shfl(xv, sl + j, 64);
    #pragma unroll
    for (int nt = 0; nt < 2; ++nt) {
      const int d = dbase + 16 * nt + l16;
      #pragma unroll
      for (int j = 0; j < 8; ++j) q[k0][nt][j] = (uint_t)g16u[xs[j] * DD + d];
    }
  }

  float b1v[2], b2v[2];
  #pragma unroll
  for (int nt = 0; nt < 2; ++nt) {
    b1v[nt] = b1[dbase + 16 * nt + l16];
    b2v[nt] = b2[cbase + 16 * nt + l16];
  }

  __syncthreads();   // flags zeroed before any wave can publish

  // Build B-fragments (q dies here): pack pairs with one lshl_or each.
  half8 bf[2][2];
  #pragma unroll
  for (int k0 = 0; k0 < 2; ++k0)
    #pragma unroll
    for (int nt = 0; nt < 2; ++nt) {
      u4h8 h;
      #pragma unroll
      for (int p = 0; p < 4; ++p)
        h.u[p] = q[k0][nt][2 * p] | (q[k0][nt][2 * p + 1] << 16);
      bf[k0][nt] = h.v;
    }

  // --- P2+P3 fused, mt-outer: MFMA tile then its tanh/cvt/store ---
  #pragma unroll
  for (int mt = 0; mt < 4; ++mt) {
    f32x4 a1[2];
    a1[0] = (f32x4)0.0f;
    a1[1] = (f32x4)0.0f;
    #pragma unroll
    for (int k0 = 0; k0 < 2; ++k0) {
      const int sl = k0 * 32 + quad * 8;
      const int t  = mt * 16 + l16;
      half8 ah = *(const half8*)(A16 + t * WIN + sl);   // L1-resident
      #pragma unroll
      for (int nt = 0; nt < 2; ++nt)
        a1[nt] = __builtin_amdgcn_mfma_f32_16x16x32_f16(ah, bf[k0][nt], a1[nt], 0, 0, 0);
    }
    // P3 for this mt: tanh(+b1), cvt f16, swizzled store.
    const int wsw = (quad & 2) << 3;    // row-bit3 of tl -> XOR 16 halfs
    #pragma unroll
    for (int nt = 0; nt < 2; ++nt) {
      const int ds = (dbase + 16 * nt + l16) ^ wsw;
      #pragma unroll
      for (int r = 0; r < 4; ++r) {
        const int tl = mt * 16 + quad * 4 + r;
        H16[tl][ds] = (half_t)fast_tanh(a1[nt][r] + b1v[nt]);
      }
    }
  }

  // Publish this wave's d-slice (release: drains the ds_writes first).
  __hip_atomic_store(&ready[w], 1, __ATOMIC_RELEASE, __HIP_MEMORY_SCOPE_WORKGROUP);

  // --- P4: matmul2 MFMA, rotated k0 (start at own slice), W2 dbuf ring ---
  f32x4 acc2[4][2];
  #pragma unroll
  for (int mt = 0; mt < 4; ++mt)
    #pragma unroll
    for (int nt = 0; nt < 2; ++nt) acc2[mt][nt] = (f32x4)0.0f;

  half8 wf[2][2];
  {
    const int dsl0 = w * 32 + quad * 8;   // first k0 = own slice
    #pragma unroll
    for (int nt = 0; nt < 2; ++nt) {
      const int c = cbase + 16 * nt + l16;
      wf[0][nt] = *(const half8*)(W216 + c * DD + dsl0);
    }
  }

  #pragma unroll 2
  for (int kk = 0; kk < 8; ++kk) {
    const int k0  = (w + kk) & 7;
    const int cur = kk & 1, nxt = cur ^ 1;
    if (kk < 7) {
      const int dsln = ((w + kk + 1) & 7) * 32 + quad * 8;
      #pragma unroll
      for (int nt = 0; nt < 2; ++nt) {
        const int c = cbase + 16 * nt + l16;
        wf[nxt][nt] = *(const half8*)(W216 + c * DD + dsln);   // prefetch kk+1
      }
    }
    // Wait for slice k0's producer (kk==0 -> own slice, succeeds instantly).
    while (__hip_atomic_load(&ready[k0], __ATOMIC_ACQUIRE,
                             __HIP_MEMORY_SCOPE_WORKGROUP) == 0) { }
    const int dsw = (k0 * 32 + quad * 8) ^ rsw;   // un-swizzled read col
    __builtin_amdgcn_s_setprio(1);
    #pragma unroll
    for (int mt = 0; mt < 4; ++mt) {
      const int t = mt * 16 + l16;
      half8 ah = *(const half8*)(&H16[t][dsw]);   // ds_read_b128
      #pragma unroll
      for (int nt = 0; nt < 2; ++nt)
        acc2[mt][nt] = __builtin_amdgcn_mfma_f32_16x16x32_f16(ah, wf[cur][nt], acc2[mt][nt], 0, 0, 0);
    }
    __builtin_amdgcn_s_setprio(0);
  }

  // --- P5: tanh(+b2) + token-sum, one atomic per (b,c) ---
  #pragma unroll
  for (int nt = 0; nt < 2; ++nt) {
    float p = 0.0f;
    #pragma unroll
    for (int mt = 0; mt < 4; ++mt)
      #pragma unroll
      for (int r = 0; r < 4; ++r)
        p += fast_tanh(acc2[mt][nt][r] + b2v[nt]);
    p += __shfl_xor(p, 16, 64);
    p += __shfl_xor(p, 32, 64);
    if (quad == 0) atomicAdd(&pool[b * DD + cbase + 16 * nt + l16], p);
  }
}

// ---------------------------------------------------------------------------
// Final: out[b,c] = (pool[b,:] / S) . Wc[c,:] + bc[c].  One block per b.
// ---------------------------------------------------------------------------
__global__ __launch_bounds__(64) void final_kernel(
    const float* __restrict__ pool, const float* __restrict__ Wc,
    const float* __restrict__ bc, float* __restrict__ out)
{
  const int b = blockIdx.x;
  const int t = threadIdx.x;
  float p0 = 0.0f, p1 = 0.0f;
  #pragma unroll
  for (int j = 0; j < 4; ++j) {
    float pv = pool[b * DD + t + 64 * j];
    p0 += pv * Wc[t + 64 * j];
    p1 += pv * Wc[DD + t + 64 * j];
  }
  #pragma unroll
  for (int off = 32; off; off >>= 1) {
    p0 += __shfl_xor(p0, off, 64);
    p1 += __shfl_xor(p1, off, 64);
  }
  if (t == 0) {
    out[b * CC + 0] = p0 * (1.0f / SS) + bc[0];
    out[b * CC + 1] = p1 * (1.0f / SS) + bc[1];
  }
}

extern "C" void kernel_launch(void* const* d_in, const int* in_sizes, int n_in,
                              void* d_out, int out_size, void* d_ws, size_t ws_size,
                              hipStream_t stream) {
  const int*   x   = (const int*)  d_in[0];
  const float* emb = (const float*)d_in[1];
  const float* W1  = (const float*)d_in[2];
  const float* b1  = (const float*)d_in[3];
  const float* W2  = (const float*)d_in[4];
  const float* b2  = (const float*)d_in[5];
  const float* Wc  = (const float*)d_in[6];
  const float* bc  = (const float*)d_in[7];
  float* out = (float*)d_out;
  char*  ws  = (char*)d_ws;

  prep_kernel<<<1090, 256, 0, stream>>>(emb, W1, W2, ws);
  main_kernel<<<BB * NW, 512, 0, stream>>>(
      x,
      (const ushort_t*)(ws + WS_G16_B),
      (const half_t*)  (ws + WS_A16_B),
      b1,
      (const half_t*)  (ws + WS_W216_B),
      b2,
      (float*)(ws + WS_POOL_B));
  final_kernel<<<BB, 64, 0, stream>>>((const float*)(ws + WS_POOL_B), Wc, bc, out);
}

// Round 8
// 134.481 us; speedup vs baseline: 2.9713x; 1.0007x over previous
//
#include <hip/hip_runtime.h>
#include <hip/hip_bf16.h>
#include <math.h>

// Problem constants (match reference)
#define BB  32
#define SS  4096
#define VV  256
#define DD  256
#define CC  2
#define WIN 64
#define NW  64   // SS/WIN

typedef unsigned short ushort_t;
typedef unsigned int   uint_t;
typedef _Float16 half_t;
typedef __attribute__((ext_vector_type(8))) _Float16 half8;   // 8 f16 (4 VGPRs)
typedef __attribute__((ext_vector_type(4))) float f32x4;

// Workspace layout (byte offsets). Total 303104 B (fits prior 573440 ws).
#define WS_A16_B  0u          // half A16[64][64]     8192  (A-op layout: [t][s])
#define WS_G16_B  8192u       // half g16[256][256]   131072
#define WS_W216_B 139264u     // half W216[256][256]  131072
#define WS_POOL_B 270336u     // float pool[32][256]  32768

#define HP 264    // H plane row stride in halfs (256 + 8 pad; row = 528 B = 33*16)

__device__ __forceinline__ float fast_tanh(float v) {
  float e = __expf(2.0f * v);
  return 1.0f - __fdividef(2.0f, e + 1.0f);
}

union u4h8 { uint_t u[4]; half8 v; };

// ---------------------------------------------------------------------------
// Prep grid (1090 blocks): unchanged from round 7 (fp16 planes, verified).
// ---------------------------------------------------------------------------
__global__ __launch_bounds__(256) void prep_kernel(
    const float* __restrict__ emb, const float* __restrict__ W1,
    const float* __restrict__ W2, char* __restrict__ ws)
{
  const int blk = blockIdx.x;
  const int tid = threadIdx.x;
  half_t* A16  = (half_t*)(ws + WS_A16_B);
  half_t* g16  = (half_t*)(ws + WS_G16_B);
  half_t* W216 = (half_t*)(ws + WS_W216_B);
  float*  pool = (float*) (ws + WS_POOL_B);

  if (blk == 0) {
    if (tid < WIN) {
      const int s = tid;
      const float omega = 60.0f * 2.0f * 3.14159265358979323846f / 4095.0f;
      float row[WIN];
      float sum = 0.0f;
      for (int t = 0; t < WIN; ++t) {
        float e = expf(cosf(omega * (float)(s - t)));
        row[t] = e;
        sum += e;
      }
      const float inv = 1.0f / sum;
      for (int t = 0; t < WIN; ++t)
        A16[t * WIN + s] = (half_t)(row[t] * inv);
    }
  } else if (blk == 1) {
    for (int i = tid; i < BB * DD; i += 256) pool[i] = 0.0f;
  } else if (blk < 1026) {
    const int gv = blk - 2;            // 0..1023
    const int d0 = (gv & 15) * 16;     // 16 d-columns
    const int v0 = (gv >> 4) * 4;      // 4 v-rows
    __shared__ float er[4 * DD];       // 4 KB
    __shared__ float ps[4][16][17];    // padded partials
    *(float4*)(er + tid * 4) = *(const float4*)(emb + v0 * DD + tid * 4);
    __syncthreads();
    const int kq = tid & 15;           // k-strip: [16kq, 16kq+16)
    const int dl = tid >> 4;           // 0..15
    const int d  = d0 + dl;
    float4 wv[4];
    #pragma unroll
    for (int j = 0; j < 4; ++j)
      wv[j] = *(const float4*)(W1 + d * DD + 16 * kq + 4 * j);  // coalesced
    #pragma unroll
    for (int v = 0; v < 4; ++v) {
      float a = 0.0f;
      #pragma unroll
      for (int j = 0; j < 4; ++j) {
        float4 e = *(const float4*)(er + v * DD + 16 * kq + 4 * j);
        a += e.x * wv[j].x + e.y * wv[j].y + e.z * wv[j].z + e.w * wv[j].w;
      }
      ps[v][dl][kq] = a;
    }
    __syncthreads();
    if (tid < 64) {
      const int v = tid >> 4, dr = tid & 15;
      float s = 0.0f;
      #pragma unroll
      for (int k = 0; k < 16; ++k) s += ps[v][dr][k];
      g16[(v0 + v) * DD + d0 + dr] = (half_t)s;
    }
  } else {
    const int c0 = (blk - 1026) * 4;
    #pragma unroll
    for (int i = 0; i < 4; ++i) {
      const int c = c0 + i;
      W216[c * DD + tid] = (half_t)W2[c * DD + tid];
    }
  }
}

// ---------------------------------------------------------------------------
// Main fused kernel — round-7 fp16 kernel, ONE change: __launch_bounds__
// (512,6). Rationale: VALUBusy 66% @ Occupancy 50% (4 waves/SIMD); LDS is
// 34 KB/block (fits 4 blocks/CU); the 2-block residency is register
// ALLOCATION (the (512,4) bound let the compiler take up to 128/wave), not
// register DEMAND (~65 live regs at P4 peak). (512,6) caps allocation at 84
// -> 3 blocks/CU, +50% TLP on the VALU-critical pipe.
// Failure modes: coarse HW reg quantum -> neutral; spill -> WRITE_SIZE
// tripwire fires -> revert. Demand(65) < budget(84), unlike rounds 1/2/5
// where demand(~118) > cap(64).
// ---------------------------------------------------------------------------
__global__ __launch_bounds__(512, 6) void main_kernel(
    const int*      __restrict__ x,    const ushort_t* __restrict__ g16u,
    const half_t*   __restrict__ A16,  const float*    __restrict__ b1,
    const half_t*   __restrict__ W216, const float*    __restrict__ b2,
    float* __restrict__ pool)
{
  __shared__ half_t H16[WIN][HP];     // 33792 B
  __shared__ int ready[8];            // per-wave d-slice published flags

  const int tid  = threadIdx.x;
  const int lane = tid & 63;
  const int w    = tid >> 6;       // 0..7
  const int quad = lane >> 4;
  const int l16  = lane & 15;
  const int b = blockIdx.x >> 6;
  const int n = blockIdx.x & 63;

  const int dbase = 32 * w;        // this wave's d-slice (P2) == c-slice (P4)
  const int cbase = dbase;
  const int rsw   = (l16 & 8) << 1;   // P4 read un-swizzle (16 halfs)

  if (tid < 8) ready[tid] = 0;

  // --- P1: gather (fp16, ushort loads), issued first to overlap setup ---
  const int xv = x[b * SS + n * WIN + lane];
  uint_t q[2][2][8];
  #pragma unroll
  for (int k0 = 0; k0 < 2; ++k0) {
    const int sl = k0 * 32 + quad * 8;
    int xs[8];
    #pragma unroll
    for (int j = 0; j < 8; ++j) xs[j] = __shfl(xv, sl + j, 64);
    #pragma unroll
    for (int nt = 0; nt < 2; ++nt) {
      const int d = dbase + 16 * nt + l16;
      #pragma unroll
      for (int j = 0; j < 8; ++j) q[k0][nt][j] = (uint_t)g16u[xs[j] * DD + d];
    }
  }

  float b1v[2], b2v[2];
  #pragma unroll
  for (int nt = 0; nt < 2; ++nt) {
    b1v[nt] = b1[dbase + 16 * nt + l16];
    b2v[nt] = b2[cbase + 16 * nt + l16];
  }

  __syncthreads();   // flags zeroed before any wave can publish

  // Build B-fragments (q dies here): pack pairs with one lshl_or each.
  half8 bf[2][2];
  #pragma unroll
  for (int k0 = 0; k0 < 2; ++k0)
    #pragma unroll
    for (int nt = 0; nt < 2; ++nt) {
      u4h8 h;
      #pragma unroll
      for (int p = 0; p < 4; ++p)
        h.u[p] = q[k0][nt][2 * p] | (q[k0][nt][2 * p + 1] << 16);
      bf[k0][nt] = h.v;
    }

  // --- P2+P3 fused, mt-outer: MFMA tile then its tanh/cvt/store ---
  #pragma unroll
  for (int mt = 0; mt < 4; ++mt) {
    f32x4 a1[2];
    a1[0] = (f32x4)0.0f;
    a1[1] = (f32x4)0.0f;
    #pragma unroll
    for (int k0 = 0; k0 < 2; ++k0) {
      const int sl = k0 * 32 + quad * 8;
      const int t  = mt * 16 + l16;
      half8 ah = *(const half8*)(A16 + t * WIN + sl);   // L1-resident
      #pragma unroll
      for (int nt = 0; nt < 2; ++nt)
        a1[nt] = __builtin_amdgcn_mfma_f32_16x16x32_f16(ah, bf[k0][nt], a1[nt], 0, 0, 0);
    }
    // P3 for this mt: tanh(+b1), cvt f16, swizzled store.
    const int wsw = (quad & 2) << 3;    // row-bit3 of tl -> XOR 16 halfs
    #pragma unroll
    for (int nt = 0; nt < 2; ++nt) {
      const int ds = (dbase + 16 * nt + l16) ^ wsw;
      #pragma unroll
      for (int r = 0; r < 4; ++r) {
        const int tl = mt * 16 + quad * 4 + r;
        H16[tl][ds] = (half_t)fast_tanh(a1[nt][r] + b1v[nt]);
      }
    }
  }

  // Publish this wave's d-slice (release: drains the ds_writes first).
  __hip_atomic_store(&ready[w], 1, __ATOMIC_RELEASE, __HIP_MEMORY_SCOPE_WORKGROUP);

  // --- P4: matmul2 MFMA, rotated k0 (start at own slice), W2 dbuf ring ---
  f32x4 acc2[4][2];
  #pragma unroll
  for (int mt = 0; mt < 4; ++mt)
    #pragma unroll
    for (int nt = 0; nt < 2; ++nt) acc2[mt][nt] = (f32x4)0.0f;

  half8 wf[2][2];
  {
    const int dsl0 = w * 32 + quad * 8;   // first k0 = own slice
    #pragma unroll
    for (int nt = 0; nt < 2; ++nt) {
      const int c = cbase + 16 * nt + l16;
      wf[0][nt] = *(const half8*)(W216 + c * DD + dsl0);
    }
  }

  #pragma unroll 2
  for (int kk = 0; kk < 8; ++kk) {
    const int k0  = (w + kk) & 7;
    const int cur = kk & 1, nxt = cur ^ 1;
    if (kk < 7) {
      const int dsln = ((w + kk + 1) & 7) * 32 + quad * 8;
      #pragma unroll
      for (int nt = 0; nt < 2; ++nt) {
        const int c = cbase + 16 * nt + l16;
        wf[nxt][nt] = *(const half8*)(W216 + c * DD + dsln);   // prefetch kk+1
      }
    }
    // Wait for slice k0's producer (kk==0 -> own slice, succeeds instantly).
    while (__hip_atomic_load(&ready[k0], __ATOMIC_ACQUIRE,
                             __HIP_MEMORY_SCOPE_WORKGROUP) == 0) { }
    const int dsw = (k0 * 32 + quad * 8) ^ rsw;   // un-swizzled read col
    __builtin_amdgcn_s_setprio(1);
    #pragma unroll
    for (int mt = 0; mt < 4; ++mt) {
      const int t = mt * 16 + l16;
      half8 ah = *(const half8*)(&H16[t][dsw]);   // ds_read_b128
      #pragma unroll
      for (int nt = 0; nt < 2; ++nt)
        acc2[mt][nt] = __builtin_amdgcn_mfma_f32_16x16x32_f16(ah, wf[cur][nt], acc2[mt][nt], 0, 0, 0);
    }
    __builtin_amdgcn_s_setprio(0);
  }

  // --- P5: tanh(+b2) + token-sum, one atomic per (b,c) ---
  #pragma unroll
  for (int nt = 0; nt < 2; ++nt) {
    float p = 0.0f;
    #pragma unroll
    for (int mt = 0; mt < 4; ++mt)
      #pragma unroll
      for (int r = 0; r < 4; ++r)
        p += fast_tanh(acc2[mt][nt][r] + b2v[nt]);
    p += __shfl_xor(p, 16, 64);
    p += __shfl_xor(p, 32, 64);
    if (quad == 0) atomicAdd(&pool[b * DD + cbase + 16 * nt + l16], p);
  }
}

// ---------------------------------------------------------------------------
// Final: out[b,c] = (pool[b,:] / S) . Wc[c,:] + bc[c].  One block per b.
// ---------------------------------------------------------------------------
__global__ __launch_bounds__(64) void final_kernel(
    const float* __restrict__ pool, const float* __restrict__ Wc,
    const float* __restrict__ bc, float* __restrict__ out)
{
  const int b = blockIdx.x;
  const int t = threadIdx.x;
  float p0 = 0.0f, p1 = 0.0f;
  #pragma unroll
  for (int j = 0; j < 4; ++j) {
    float pv = pool[b * DD + t + 64 * j];
    p0 += pv * Wc[t + 64 * j];
    p1 += pv * Wc[DD + t + 64 * j];
  }
  #pragma unroll
  for (int off = 32; off; off >>= 1) {
    p0 += __shfl_xor(p0, off, 64);
    p1 += __shfl_xor(p1, off, 64);
  }
  if (t == 0) {
    out[b * CC + 0] = p0 * (1.0f / SS) + bc[0];
    out[b * CC + 1] = p1 * (1.0f / SS) + bc[1];
  }
}

extern "C" void kernel_launch(void* const* d_in, const int* in_sizes, int n_in,
                              void* d_out, int out_size, void* d_ws, size_t ws_size,
                              hipStream_t stream) {
  const int*   x   = (const int*)  d_in[0];
  const float* emb = (const float*)d_in[1];
  const float* W1  = (const float*)d_in[2];
  const float* b1  = (const float*)d_in[3];
  const float* W2  = (const float*)d_in[4];
  const float* b2  = (const float*)d_in[5];
  const float* Wc  = (const float*)d_in[6];
  const float* bc  = (const float*)d_in[7];
  float* out = (float*)d_out;
  char*  ws  = (char*)d_ws;

  prep_kernel<<<1090, 256, 0, stream>>>(emb, W1, W2, ws);
  main_kernel<<<BB * NW, 512, 0, stream>>>(
      x,
      (const ushort_t*)(ws + WS_G16_B),
      (const half_t*)  (ws + WS_A16_B),
      b1,
      (const half_t*)  (ws + WS_W216_B),
      b2,
      (float*)(ws + WS_POOL_B));
  final_kernel<<<BB, 64, 0, stream>>>((const float*)(ws + WS_POOL_B), Wc, bc, out);
}